// Round 14
// baseline (45.067 us; speedup 1.0000x reference)
//
#include <hip/hip_runtime.h>
#include <math.h>

constexpr int BB = 2, NN = 4096, MM = 16384;
constexpr int JS = 32;                   // col strips (512 cols each)
constexpr int IG2 = 32;                  // row groups (128 rows each)
constexpr int SC = 512;                  // cols per strip
constexpr int ST = SC / 32;              // 16 B-tiles (32 cols) per strip
constexpr unsigned INFBITS = 0x7F800000u;
constexpr ushort ONEB = 0x3F80;          // bf16 1.0

typedef __attribute__((ext_vector_type(8)))  short  short8;
typedef __attribute__((ext_vector_type(8)))  ushort ushort8;
typedef __attribute__((ext_vector_type(16))) float  f32x16;

// sq = |s|^2 + |r|^2 - 2 s.r in ONE mfma_32x32x16_bf16 K-vector (hi/lo split,
// verified absmax 0.0 in R11-R13):
//  A k0-7: {hi(-2s)x,y,z, hi(-2s)x,y,z, lo(-2s)x,y}  k8-15: {lo(-2s)z, hi|s|2, lo|s|2, 1, 1, 0,0,0}
//  B k0-7: {hi(r)x,y,z,  lo(r)x,y,z,  hi(r)x,y}     k8-15: {hi(r)z,  1, 1, hi|r|2, lo|r|2, 0,0,0}
// Fragment: lane&31 = row/col, lane>>5 = K-half. C: col=lane&31,
// row=(reg&3)+8*(reg>>2)+4*(lane>>5)  [m74/m101-verified].
__device__ __forceinline__ ushort f2bf(float f) {
    unsigned u = __float_as_uint(f);
    u += 0x7FFF + ((u >> 16) & 1);
    return (ushort)(u >> 16);
}
__device__ __forceinline__ void split2(float v, ushort& h, ushort& l) {
    h = f2bf(v);
    l = f2bf(v - __uint_as_float(((unsigned)h) << 16));
}
__device__ __forceinline__ float vmin16(const f32x16& c) {
    float a0 = fminf(fminf(c[0], c[1]),   fminf(c[2], c[3]));
    float a1 = fminf(fminf(c[4], c[5]),   fminf(c[6], c[7]));
    float a2 = fminf(fminf(c[8], c[9]),   fminf(c[10], c[11]));
    float a3 = fminf(fminf(c[12], c[13]), fminf(c[14], c[15]));
    return fminf(fminf(a0, a1), fminf(a2, a3));
}

// ---- pack raw points into global B-fragments (1 KB per 32-col tile) ----
__global__ __launch_bounds__(256) void packB_kernel(
    const float* __restrict__ raw, ushort* __restrict__ Bpack)
{
    const int g = blockIdx.x * 256 + threadIdx.x;   // 0 .. BB*MM-1
    float4 v = ((const float4*)raw)[g];
    float n = fmaf(v.z, v.z, fmaf(v.y, v.y, v.x * v.x));
    ushort hx,lx,hy,ly,hz,lz,hn,ln;
    split2(v.x, hx, lx); split2(v.y, hy, ly);
    split2(v.z, hz, lz); split2(n, hn, ln);
    ushort* dst = Bpack + ((size_t)(g >> 5) << 9) + (g & 31) * 8;
    *(ushort8*)(dst)       = ushort8{hx,hy,hz,lx,ly,lz,hx,hy};   // lanes 0-31 (K 0-7)
    *(ushort8*)(dst + 256) = ushort8{hz,ONEB,ONEB,hn,ln,0,0,0};  // lanes 32-63 (K 8-15)
}

// ---- pair: grid (JS, IG2, BB) = 2048 blocks, 4 waves; wave = 32 rows x 512 cols.
// Loop body: 1 global dwordx4 (L1-hot packed B) + 1 MFMA + 31 fmin + 1 shfl.
__global__ __launch_bounds__(256, 4) void pair_kernel(
    const float* __restrict__ sampled,   // [BB][NN][4]
    const ushort* __restrict__ Bpack,    // [BB*MM/32][512]
    float* __restrict__ rowpart,         // [JS][BB][NN]
    float* __restrict__ colpart,         // [IG2][BB][MM]
    unsigned* __restrict__ counter)
{
    __shared__ float ldsCol[4][SC];      // 8 KB

    const int js = blockIdx.x, ig = blockIdx.y, b = blockIdx.z;
    const int tid = threadIdx.x, w = tid >> 6, lane = tid & 63;
    const int half = lane >> 5;
    const int j0 = js * SC, i0 = ig * 128;

    if (js == 0 && ig == 0 && b == 0 && tid == 0) *counter = 0u;

    // ---- this wave's A-fragment (rows i0 + w*32 .. +31) in registers ----
    short8 afr;
    {
        float4 v = ((const float4*)sampled)[(size_t)b * NN + i0 + w * 32 + (lane & 31)];
        float n = fmaf(v.z, v.z, fmaf(v.y, v.y, v.x * v.x));
        ushort hx,lx,hy,ly,hz,lz,hn,ln;
        split2(-2.f * v.x, hx, lx); split2(-2.f * v.y, hy, ly);
        split2(-2.f * v.z, hz, lz); split2(n, hn, ln);
        ushort8 w0 = ushort8{hx,hy,hz,hx,hy,hz,lx,ly};
        ushort8 w1 = ushort8{lz,hn,ln,ONEB,ONEB,0,0,0};
        ushort8 sel = half ? w1 : w0;
        afr = *(short8*)&sel;
    }

    const float INF = __uint_as_float(INFBITS);
    float racc[16];
#pragma unroll
    for (int r = 0; r < 16; ++r) racc[r] = INF;

    const f32x16 zero = {0.f,0.f,0.f,0.f,0.f,0.f,0.f,0.f,
                         0.f,0.f,0.f,0.f,0.f,0.f,0.f,0.f};
    const ushort* Bb = Bpack + (((size_t)(b * (MM / 32) + js * ST)) << 9) + lane * 8;

#pragma unroll 1
    for (int jt = 0; jt < ST; ++jt) {
        short8 bf = *(const short8*)(Bb + ((size_t)jt << 9));
        f32x16 c = __builtin_amdgcn_mfma_f32_32x32x16_bf16(afr, bf, zero, 0, 0, 0);
#pragma unroll
        for (int r = 0; r < 16; ++r) racc[r] = fminf(racc[r], c[r]);
        float m = vmin16(c);                           // min over this half's 16 rows
        m = fminf(m, __shfl_xor(m, 32, 64));           // combine halves -> 32 rows
        if (lane < 32) ldsCol[w][jt * 32 + lane] = m;  // each slot written once
    }

    // ---- row mins: butterfly across the 32 cols (lane&31), plain stores ----
#pragma unroll
    for (int mask = 1; mask < 32; mask <<= 1)
#pragma unroll
        for (int r = 0; r < 16; ++r)
            racc[r] = fminf(racc[r], __shfl_xor(racc[r], mask, 64));
    if ((lane & 31) == 0) {                            // lanes 0 and 32
        float* rp = rowpart + ((size_t)js * BB + b) * NN + i0 + w * 32;
#pragma unroll
        for (int r = 0; r < 16; ++r) {
            const int row = (r & 3) + 8 * (r >> 2) + 4 * half;
            rp[row] = fmaxf(racc[r], 0.f);
        }
    }

    // ---- col mins: combine the block's 4 row-waves, plain store ----
    __syncthreads();
    float* cp = colpart + ((size_t)ig * BB + b) * MM + j0;
    for (int t = tid; t < SC; t += 256) {
        float v = fminf(fminf(ldsCol[0][t], ldsCol[1][t]),
                        fminf(ldsCol[2][t], ldsCol[3][t]));
        cp[t] = fmaxf(v, 0.f);
    }
}

// ---- 128 blocks; last block combines the 128 partials and writes out ----
__global__ __launch_bounds__(256) void reduce_kernel(
    const float* __restrict__ rowpart,
    const float* __restrict__ colpart,
    float* __restrict__ part,            // [128][3]
    unsigned* __restrict__ counter,
    float* __restrict__ out)
{
    const int k = blockIdx.x, b = k >> 6, s = k & 63;
    const int tid = threadIdx.x;
    const float INF = __uint_as_float(INFBITS);

    const int col = s * 256 + tid;
    float v = INF;
#pragma unroll 4
    for (int ig = 0; ig < IG2; ++ig)
        v = fminf(v, colpart[((size_t)ig * BB + b) * MM + col]);
    float sB = sqrtf(v);

    const int row = s * 64 + (tid & 63);
    const int jq  = tid >> 6;
    float wv2 = INF;
#pragma unroll
    for (int q = 0; q < JS / 4; ++q)
        wv2 = fminf(wv2, rowpart[((size_t)(jq * (JS / 4) + q) * BB + b) * NN + row]);
    __shared__ float rred[4][64];
    rred[jq][tid & 63] = wv2;
    __syncthreads();
    float sF = 0.f, mF = 0.f;
    if (tid < 64) {
        float rmn = fminf(fminf(rred[0][tid], rred[1][tid]),
                          fminf(rred[2][tid], rred[3][tid]));
        float d = sqrtf(rmn);
        sF = d; mF = d;
    }

    for (int m = 1; m < 64; m <<= 1) {
        sB += __shfl_xor(sB, m, 64);
        sF += __shfl_xor(sF, m, 64);
        mF = fmaxf(mF, __shfl_xor(mF, m, 64));
    }
    __shared__ float red[3][4];
    const int lane = tid & 63, wvi = tid >> 6;
    if (lane == 0) { red[0][wvi] = sB; red[1][wvi] = sF; red[2][wvi] = mF; }
    __syncthreads();

    __shared__ bool isLast;
    if (tid == 0) {
        part[k * 3 + 0] = red[0][0] + red[0][1] + red[0][2] + red[0][3];
        part[k * 3 + 1] = red[1][0] + red[1][1] + red[1][2] + red[1][3];
        part[k * 3 + 2] = fmaxf(fmaxf(red[2][0], red[2][1]),
                                fmaxf(red[2][2], red[2][3]));
        __threadfence();
        isLast = (atomicAdd(counter, 1u) == 127u);
    }
    __syncthreads();
    if (!isLast) return;

    __threadfence();
    volatile const float* vp = part;
    float fB = 0.f, fF = 0.f, fM = 0.f;
    if (tid < 128) {
        fB = vp[tid * 3 + 0]; fF = vp[tid * 3 + 1]; fM = vp[tid * 3 + 2];
    }
    for (int m = 1; m < 64; m <<= 1) {
        fB += __shfl_xor(fB, m, 64);
        fF += __shfl_xor(fF, m, 64);
        fM = fmaxf(fM, __shfl_xor(fM, m, 64));
    }
    __shared__ float fin[2][3];
    if (tid < 128 && (tid & 63) == 0) {
        fin[tid >> 6][0] = fB; fin[tid >> 6][1] = fF; fin[tid >> 6][2] = fM;
    }
    __syncthreads();
    if (tid == 0) {
        float l0 = 5.f * fin[0][0] / (float)MM + fin[0][1] / (float)NN + fin[0][2];
        float l1 = 5.f * fin[1][0] / (float)MM + fin[1][1] / (float)NN + fin[1][2];
        *out = 0.5f * (l0 + l1);
    }
}

extern "C" void kernel_launch(void* const* d_in, const int* in_sizes, int n_in,
                              void* d_out, int out_size, void* d_ws, size_t ws_size,
                              hipStream_t stream) {
    const float* sampled = (const float*)d_in[0];
    const float* raw     = (const float*)d_in[1];
    ushort* Bpack  = (ushort*)d_ws;                          // BB*MM/32 tiles * 1 KB = 1 MB
    float* rowpart = (float*)(Bpack + (size_t)BB * MM * 16); // JS*BB*NN  = 1 MB
    float* colpart = rowpart + (size_t)JS * BB * NN;         // IG2*BB*MM = 4 MB
    float* part    = colpart + (size_t)IG2 * BB * MM;
    unsigned* counter = (unsigned*)(part + 3 * 128);
    float* out     = (float*)d_out;

    packB_kernel<<<(BB * MM) / 256, 256, 0, stream>>>(raw, Bpack);
    pair_kernel<<<dim3(JS, IG2, BB), 256, 0, stream>>>(sampled, Bpack, rowpart, colpart, counter);
    reduce_kernel<<<128, 256, 0, stream>>>(rowpart, colpart, part, counter, out);
}

// Round 15
// 34.381 us; speedup vs baseline: 1.3108x; 1.3108x over previous
//
#include <hip/hip_runtime.h>
#include <math.h>

constexpr int BB = 2, NN = 4096, MM = 16384;
constexpr int CSL = 4;                   // col-pass slices over N (1024 sampled each)
constexpr int RSL = 16;                  // row-pass slices over M (1024 raw each)
constexpr unsigned INFBITS = 0x7F800000u;
constexpr ushort ONEB = 0x3F80;          // bf16 1.0

typedef __attribute__((ext_vector_type(8)))  short  short8;
typedef __attribute__((ext_vector_type(8)))  ushort ushort8;
typedef __attribute__((ext_vector_type(16))) float  f32x16;

// sq = |p|^2 + |q|^2 - 2 p.q in ONE mfma_32x32x16_bf16 K-vector (hi/lo split,
// verified absmax 0.0 in R11-R14). Generic two-sided encoding:
//  A-side(p): k0-5 hi(-2p)xyz x2, k6-8 lo(-2p), k9-10 hi/lo|p|^2, k11-12 1, k13-15 0
//  B-side(q): k0-2 hi(q), k3-5 lo(q), k6-8 hi(q), k9-10 1, k11-12 hi/lo|q|^2, 0
// Key asymmetry used here: C col=lane&31 (B point), row=reg (A point) -> min
// over the STREAMED A index is cross-REG (vmin16, free); the owned B point
// stays in the lane => single-register accumulator, no in-loop cross-lane.
__device__ __forceinline__ ushort f2bf(float f) {
    unsigned u = __float_as_uint(f);
    u += 0x7FFF + ((u >> 16) & 1);
    return (ushort)(u >> 16);
}
__device__ __forceinline__ void split2(float v, ushort& h, ushort& l) {
    h = f2bf(v);
    l = f2bf(v - __uint_as_float(((unsigned)h) << 16));
}
__device__ __forceinline__ float vmin16(const f32x16& c) {
    float a0 = fminf(fminf(c[0], c[1]),   fminf(c[2], c[3]));
    float a1 = fminf(fminf(c[4], c[5]),   fminf(c[6], c[7]));
    float a2 = fminf(fminf(c[8], c[9]),   fminf(c[10], c[11]));
    float a3 = fminf(fminf(c[12], c[13]), fminf(c[14], c[15]));
    return fminf(fminf(a0, a1), fminf(a2, a3));
}

// ---- pack the STREAMED A-side fragments to global (tile = 32 pts, 1 KB) ----
__global__ __launch_bounds__(256) void pack_kernel(
    const float* __restrict__ sampled, const float* __restrict__ raw,
    ushort* __restrict__ As, ushort* __restrict__ Ar,
    unsigned* __restrict__ counter)
{
    const int g = blockIdx.x * 256 + threadIdx.x;   // 0 .. BB*(NN+MM)-1
    if (g == 0) *counter = 0u;
    float4 v;
    ushort* dst;
    if (g < BB * NN) {
        v = ((const float4*)sampled)[g];
        dst = As + ((size_t)(g >> 5) << 9) + (g & 31) * 8;
    } else {
        const int p = g - BB * NN;
        v = ((const float4*)raw)[p];
        dst = Ar + ((size_t)(p >> 5) << 9) + (p & 31) * 8;
    }
    float n = fmaf(v.z, v.z, fmaf(v.y, v.y, v.x * v.x));
    ushort hx,lx,hy,ly,hz,lz,hn,ln;
    split2(-2.f * v.x, hx, lx); split2(-2.f * v.y, hy, ly);
    split2(-2.f * v.z, hz, lz); split2(n, hn, ln);
    *(ushort8*)(dst)       = ushort8{hx,hy,hz,hx,hy,hz,lx,ly};   // K 0-7
    *(ushort8*)(dst + 256) = ushort8{lz,hn,ln,ONEB,ONEB,0,0,0};  // K 8-15
}

// ---- pair: 2048 blocks x 4 waves; wave owns 32 points (B-frag in regs),
// streams 32 packed A-tiles; loop = load + MFMA + vmin16 + 1 fmin. ----
__global__ __launch_bounds__(256) void pair_kernel(
    const float* __restrict__ sampled,   // [BB][NN][4]
    const float* __restrict__ raw,       // [BB][MM][4]
    const ushort* __restrict__ As, const ushort* __restrict__ Ar,
    float* __restrict__ rowpart,         // [RSL][BB][NN]
    float* __restrict__ colpart)         // [CSL][BB][MM]
{
    const int gx = blockIdx.x, tid = threadIdx.x;
    const int w = tid >> 6, lane = tid & 63, half = lane >> 5, l31 = lane & 31;
    const float INF = __uint_as_float(INFBITS);
    const f32x16 zero = {0.f,0.f,0.f,0.f,0.f,0.f,0.f,0.f,
                         0.f,0.f,0.f,0.f,0.f,0.f,0.f,0.f};

    int b, base, sl;
    const ushort* Ap;
    float4 v;
    float* outp;
    if (gx < 1024) {                       // col pass: own raw, stream sampled
        int idx = gx; b = idx >> 9; idx &= 511;
        const int og = idx >> 2; sl = idx & 3;
        base = og * 128 + w * 32;
        v = ((const float4*)raw)[(size_t)b * MM + base + l31];
        Ap = As + ((size_t)(b * (NN / 32) + sl * 32) << 9) + lane * 8;
        outp = colpart + ((size_t)sl * BB + b) * MM + base;
    } else {                               // row pass: own sampled, stream raw
        int idx = gx - 1024; b = idx >> 9; idx &= 511;
        const int og = idx >> 4; sl = idx & 15;
        base = og * 128 + w * 32;
        v = ((const float4*)sampled)[(size_t)b * NN + base + l31];
        Ap = Ar + ((size_t)(b * (MM / 32) + sl * 32) << 9) + lane * 8;
        outp = rowpart + ((size_t)sl * BB + b) * NN + base;
    }

    // owned B-side fragment (lane&31 = owned point, lane>>5 = K-half)
    short8 bfr;
    {
        float n = fmaf(v.z, v.z, fmaf(v.y, v.y, v.x * v.x));
        ushort hx,lx,hy,ly,hz,lz,hn,ln;
        split2(v.x, hx, lx); split2(v.y, hy, ly);
        split2(v.z, hz, lz); split2(n, hn, ln);
        ushort8 w0 = ushort8{hx,hy,hz,lx,ly,lz,hx,hy};
        ushort8 w1 = ushort8{hz,ONEB,ONEB,hn,ln,0,0,0};
        ushort8 sel = half ? w1 : w0;
        bfr = *(short8*)&sel;
    }

    float acc = INF;
#pragma unroll 2
    for (int t = 0; t < 32; ++t) {
        short8 af = *(const short8*)(Ap + ((size_t)t << 9));
        f32x16 c = __builtin_amdgcn_mfma_f32_32x32x16_bf16(af, bfr, zero, 0, 0, 0);
        acc = fminf(acc, vmin16(c));       // min over the tile's 32 streamed pts
    }
    acc = fminf(acc, __shfl_xor(acc, 32, 64));   // combine the two row-halves
    if (lane < 32) outp[lane] = fmaxf(acc, 0.f); // each slot written by one wave
}

// ---- 128 blocks; last block combines the 128 partials and writes out ----
__global__ __launch_bounds__(256) void reduce_kernel(
    const float* __restrict__ rowpart,
    const float* __restrict__ colpart,
    float* __restrict__ part,            // [128][3]
    unsigned* __restrict__ counter,
    float* __restrict__ out)
{
    const int k = blockIdx.x, b = k >> 6, s = k & 63;
    const int tid = threadIdx.x;
    const float INF = __uint_as_float(INFBITS);

    const int col = s * 256 + tid;
    float v = INF;
#pragma unroll
    for (int sl = 0; sl < CSL; ++sl)
        v = fminf(v, colpart[((size_t)sl * BB + b) * MM + col]);
    float sB = sqrtf(v);

    const int row = s * 64 + (tid & 63);
    const int jq  = tid >> 6;
    float wv2 = INF;
#pragma unroll
    for (int q = 0; q < RSL / 4; ++q)
        wv2 = fminf(wv2, rowpart[((size_t)(jq * (RSL / 4) + q) * BB + b) * NN + row]);
    __shared__ float rred[4][64];
    rred[jq][tid & 63] = wv2;
    __syncthreads();
    float sF = 0.f, mF = 0.f;
    if (tid < 64) {
        float rmn = fminf(fminf(rred[0][tid], rred[1][tid]),
                          fminf(rred[2][tid], rred[3][tid]));
        float d = sqrtf(rmn);
        sF = d; mF = d;
    }

    for (int m = 1; m < 64; m <<= 1) {
        sB += __shfl_xor(sB, m, 64);
        sF += __shfl_xor(sF, m, 64);
        mF = fmaxf(mF, __shfl_xor(mF, m, 64));
    }
    __shared__ float red[3][4];
    const int lane = tid & 63, wvi = tid >> 6;
    if (lane == 0) { red[0][wvi] = sB; red[1][wvi] = sF; red[2][wvi] = mF; }
    __syncthreads();

    __shared__ bool isLast;
    if (tid == 0) {
        part[k * 3 + 0] = red[0][0] + red[0][1] + red[0][2] + red[0][3];
        part[k * 3 + 1] = red[1][0] + red[1][1] + red[1][2] + red[1][3];
        part[k * 3 + 2] = fmaxf(fmaxf(red[2][0], red[2][1]),
                                fmaxf(red[2][2], red[2][3]));
        __threadfence();
        isLast = (atomicAdd(counter, 1u) == 127u);
    }
    __syncthreads();
    if (!isLast) return;

    __threadfence();
    volatile const float* vp = part;
    float fB = 0.f, fF = 0.f, fM = 0.f;
    if (tid < 128) {
        fB = vp[tid * 3 + 0]; fF = vp[tid * 3 + 1]; fM = vp[tid * 3 + 2];
    }
    for (int m = 1; m < 64; m <<= 1) {
        fB += __shfl_xor(fB, m, 64);
        fF += __shfl_xor(fF, m, 64);
        fM = fmaxf(fM, __shfl_xor(fM, m, 64));
    }
    __shared__ float fin[2][3];
    if (tid < 128 && (tid & 63) == 0) {
        fin[tid >> 6][0] = fB; fin[tid >> 6][1] = fF; fin[tid >> 6][2] = fM;
    }
    __syncthreads();
    if (tid == 0) {
        float l0 = 5.f * fin[0][0] / (float)MM + fin[0][1] / (float)NN + fin[0][2];
        float l1 = 5.f * fin[1][0] / (float)MM + fin[1][1] / (float)NN + fin[1][2];
        *out = 0.5f * (l0 + l1);
    }
}

extern "C" void kernel_launch(void* const* d_in, const int* in_sizes, int n_in,
                              void* d_out, int out_size, void* d_ws, size_t ws_size,
                              hipStream_t stream) {
    const float* sampled = (const float*)d_in[0];
    const float* raw     = (const float*)d_in[1];
    ushort* As     = (ushort*)d_ws;                          // BB*NN*32B = 256 KB
    ushort* Ar     = As + (size_t)BB * NN * 16;              // BB*MM*32B = 1 MB
    float* colpart = (float*)(Ar + (size_t)BB * MM * 16);    // CSL*BB*MM = 512 KB
    float* rowpart = colpart + (size_t)CSL * BB * MM;        // RSL*BB*NN = 512 KB
    float* part    = rowpart + (size_t)RSL * BB * NN;
    unsigned* counter = (unsigned*)(part + 3 * 128);
    float* out     = (float*)d_out;

    pack_kernel<<<(BB * (NN + MM)) / 256, 256, 0, stream>>>(sampled, raw, As, Ar, counter);
    pair_kernel<<<2048, 256, 0, stream>>>(sampled, raw, As, Ar, rowpart, colpart);
    reduce_kernel<<<128, 256, 0, stream>>>(rowpart, colpart, part, counter, out);
}